// Round 1
// baseline (837.672 us; speedup 1.0000x reference)
//
#include <hip/hip_runtime.h>
#include <math.h>

typedef unsigned short u16;
typedef unsigned int u32;
typedef __attribute__((ext_vector_type(8))) short short8;   // 8 bf16 = 4 VGPRs
typedef __attribute__((ext_vector_type(4))) float float4v;  // MFMA accum

// ---------- constants ----------
#define BATCH   8192
#define OBS     21
#define HID     512
#define NL      10
#define OVERALL 5632            // HID*(NL+1)
#define IN_DIM  5653            // OBS + OVERALL
#define ACT     8

// output element offsets (flat concat, fp32 elements)
#define O_PM   0
#define O_LS   65536
#define O_NH   131072
#define O_NM   (131072 + BATCH*OVERALL)     // 46268416
#define O_NLS  (O_NM + 65536)               // 46333952

// packed workspace: 10 x 512 x 512 bf16 weight blocks (K-contiguous)
#define WSP_TOTAL (10*512*512)
#define WSP_BYTES ((size_t)WSP_TOTAL * 2)

__device__ __forceinline__ u16 f2bf(float f) {
    u32 u = __float_as_uint(f);
    u32 r = (u + 0x7fffu + ((u >> 16) & 1u)) >> 16;   // RNE
    return (u16)r;
}
__device__ __forceinline__ u32 pkbf(float a, float b) {
    return (u32)f2bf(a) | ((u32)f2bf(b) << 16);
}

// ---------- kernel 0: repack banded W_mean blocks fp32 -> bf16 ----------
__global__ __launch_bounds__(256) void k_pack(const float* __restrict__ Wm,
                                              u16* __restrict__ ws) {
    int idx = blockIdx.x * 256 + threadIdx.x;
    if (idx >= WSP_TOTAL) return;
    int z = idx >> 18;
    int rem = idx & 262143;
    int n = rem >> 9, k = rem & 511;
    float v = Wm[(size_t)(512 * (z + 1) + n) * IN_DIM + OBS + 512 * z + k];
    ws[idx] = f2bf(v);
}

// ---------- kernel 1: fused slice kernel -----------------------------------
// grid (128, 11): block = 64 batch rows (gm) x one 512-col X slice (z).
// Structure: stage A (64x512) bf16 in LDS ONCE (xor-swizzled), one barrier,
// then a barrier-free K loop: B fragments loaded direct global->reg from the
// packed bf16 workspace (L2-resident), 16 MFMA per wave per K-step.
//  z<10 : GEMM band z+1 (BN=512) + logstd partial (waves 0-3)
//  z==10: logstd partial (waves 0-3) + new_mean band 11 (waves 4-7)
#define BM 64
__global__ __launch_bounds__(512, 4) void k_fused(
        const float* __restrict__ X,
        const float* __restrict__ Wm_raw,
        const u16* __restrict__ Wp,
        const float* __restrict__ Wls_raw,
        const float* __restrict__ b_mean,
        float* __restrict__ out_h,
        float* __restrict__ out_ls,
        float* __restrict__ out_mean,
        int packed) {
    // 64 rows x 512 k bf16, 16-B chunks xor-swizzled by (row&7): 64 KB exactly
    __shared__ __attribute__((aligned(16))) u16 As[64 * 512];

    const int t = threadIdx.x;
    const int w = t >> 6, lane = t & 63;
    const int quad = lane >> 4, r16 = lane & 15;
    const int gm = blockIdx.x * BM;
    const int z = blockIdx.y;
    const bool mainz = (z < 10);

    // ---- stage A: each wave-iter u covers one full row (64 x 16B chunks) ----
    {
        const float* xb = X + (size_t)gm * OVERALL + (size_t)z * 512;
#pragma unroll
        for (int u = 0; u < 8; ++u) {
            int row = u * 8 + w;                       // w < 8, row 0..63
            const float* g = xb + (size_t)row * OVERALL + lane * 8;
            float4 f0 = *(const float4*)g;
            float4 f1 = *(const float4*)(g + 4);
            uint4 p;
            p.x = pkbf(f0.x, f0.y); p.y = pkbf(f0.z, f0.w);
            p.z = pkbf(f1.x, f1.y); p.w = pkbf(f1.z, f1.w);
            // chunk index = lane, physical = lane ^ (row&7) = lane ^ w
            *(uint4*)&As[row * 512 + ((lane ^ w) << 3)] = p;
        }
    }
    __syncthreads();                                    // the ONLY barrier

    float4v acc[4][4];
#pragma unroll
    for (int i = 0; i < 4; ++i)
#pragma unroll
        for (int j = 0; j < 4; ++j) acc[i][j] = (float4v)0.f;
    float4v accE = (float4v)0.f;   // logstd (w<4) or mean (z==10, w>=4)

    const int n8 = r16 & 7;        // extra-operand row (dup for r16>=8, unused)
    const u16* bp = Wp + (size_t)z * 262144
                       + (size_t)(w * 64 + r16) * 512 + quad * 8;
    const float* gL = Wls_raw + (size_t)n8 * IN_DIM + OBS + z * 512 + quad * 8;
    const float* gM = Wm_raw + (size_t)(OVERALL + n8) * IN_DIM + OBS + z * 512 + quad * 8;

#pragma unroll 4
    for (int it = 0; it < 16; ++it) {
        const int k0 = it * 32;
        const int phys = ((it * 4 + quad) ^ (r16 & 7)) << 3;   // u16 index in row
        short8 a[4];
#pragma unroll
        for (int i2 = 0; i2 < 4; ++i2) {
            int row = i2 * 16 + r16;
            a[i2] = *(const short8*)&As[row * 512 + phys];
        }
        if (mainz) {
            short8 b[4];
            if (packed) {
#pragma unroll
                for (int j = 0; j < 4; ++j)
                    b[j] = *(const short8*)(bp + j * 8192 + k0);
            } else {
#pragma unroll
                for (int j = 0; j < 4; ++j) {
                    const float* g = Wm_raw
                        + (size_t)(512 * (z + 1) + w * 64 + j * 16 + r16) * IN_DIM
                        + OBS + (size_t)z * 512 + k0 + quad * 8;
                    union { short8 s; uint4 u; } cb;
                    cb.u.x = pkbf(g[0], g[1]); cb.u.y = pkbf(g[2], g[3]);
                    cb.u.z = pkbf(g[4], g[5]); cb.u.w = pkbf(g[6], g[7]);
                    b[j] = cb.s;
                }
            }
#pragma unroll
            for (int i2 = 0; i2 < 4; ++i2)
#pragma unroll
                for (int j = 0; j < 4; ++j)
                    acc[i2][j] = __builtin_amdgcn_mfma_f32_16x16x32_bf16(
                        a[i2], b[j], acc[i2][j], 0, 0, 0);
        }
        if (w < 4) {                 // logstd partial: wave w owns rows w*16..+15
            const float* g = gL + k0;          // 4-B aligned only -> scalar loads
            union { short8 s; uint4 u; } ce;
            ce.u.x = pkbf(g[0], g[1]); ce.u.y = pkbf(g[2], g[3]);
            ce.u.z = pkbf(g[4], g[5]); ce.u.w = pkbf(g[6], g[7]);
            accE = __builtin_amdgcn_mfma_f32_16x16x32_bf16(a[w], ce.s, accE, 0, 0, 0);
        } else if (!mainz) {         // mean band: wave w-4 owns rows (w-4)*16..
            const float* g = gM + k0;
            union { short8 s; uint4 u; } ce;
            ce.u.x = pkbf(g[0], g[1]); ce.u.y = pkbf(g[2], g[3]);
            ce.u.z = pkbf(g[4], g[5]); ce.u.w = pkbf(g[6], g[7]);
            accE = __builtin_amdgcn_mfma_f32_16x16x32_bf16(a[w - 4], ce.s, accE, 0, 0, 0);
        }
    }

    // ---- epilogues.  C/D layout: col = lane&15, row = quad*4 + reg ----
    if (mainz) {
        int colblock = (z + 1) * 512;
#pragma unroll
        for (int j = 0; j < 4; ++j) {
            int n_loc = w * 64 + j * 16 + r16;
            float bias = b_mean[colblock + n_loc];
#pragma unroll
            for (int i2 = 0; i2 < 4; ++i2) {
                int m0 = gm + i2 * 16 + quad * 4;
#pragma unroll
                for (int r = 0; r < 4; ++r) {
                    float v = acc[i2][j][r] + bias;
                    out_h[(size_t)(m0 + r) * OVERALL + colblock + n_loc] = fmaxf(v, 0.f);
                }
            }
        }
    }
    if (w < 4) {                             // logstd partial -> atomic
        if (r16 < ACT) {
#pragma unroll
            for (int r = 0; r < 4; ++r) {
                int row = gm + w * 16 + quad * 4 + r;
                atomicAdd(&out_ls[(size_t)row * ACT + r16], accE[r]);
            }
        }
    } else if (!mainz) {                     // mean: exact, direct store
        if (r16 < ACT) {
            float bias = b_mean[OVERALL + r16];
#pragma unroll
            for (int r = 0; r < 4; ++r) {
                int row = gm + (w - 4) * 16 + quad * 4 + r;
                out_mean[(size_t)row * ACT + r16] = accE[r] + bias;
            }
        }
    }
}

// ---------- kernel 2: band block 0 (obs -> new_hidden cols 0..511) ----------
#define B0_ROWS 32
__global__ __launch_bounds__(256) void k_block0(const float* __restrict__ obs,
                                                const float* __restrict__ Wm,
                                                const float* __restrict__ b_mean,
                                                float* __restrict__ out_h) {
    __shared__ float w0[OBS * 512];           // transposed [k][n]
    __shared__ float bias_s[512];
    __shared__ float obs_s[B0_ROWS * OBS];
    int t = threadIdx.x;
    int b0 = blockIdx.x * B0_ROWS;
    for (int i = t; i < OBS * 512; i += 256) {
        int n = i / OBS, k = i - n * OBS;
        w0[k * 512 + n] = Wm[(size_t)n * IN_DIM + k];
    }
    for (int i = t; i < 512; i += 256) bias_s[i] = b_mean[i];
    for (int i = t; i < B0_ROWS * OBS; i += 256) obs_s[i] = obs[(size_t)b0 * OBS + i];
    __syncthreads();

    int n0 = (t & 127) * 4;
    int rh = t >> 7;
#pragma unroll 4
    for (int r = 0; r < 16; r++) {
        int row = rh * 16 + r;
        float acc0 = bias_s[n0], acc1 = bias_s[n0 + 1];
        float acc2 = bias_s[n0 + 2], acc3 = bias_s[n0 + 3];
#pragma unroll
        for (int k = 0; k < OBS; k++) {
            float xo = obs_s[row * OBS + k];
            const float* wr = &w0[k * 512 + n0];
            acc0 += xo * wr[0]; acc1 += xo * wr[1];
            acc2 += xo * wr[2]; acc3 += xo * wr[3];
        }
        float4 o;
        o.x = fmaxf(acc0, 0.f); o.y = fmaxf(acc1, 0.f);
        o.z = fmaxf(acc2, 0.f); o.w = fmaxf(acc3, 0.f);
        *(float4*)&out_h[(size_t)(b0 + row) * OVERALL + n0] = o;
    }
}

// ---------- kernel 3: finisher: logstd obs-part + bias, tanh, copy ----------
__global__ __launch_bounds__(256) void k_finish(const float* __restrict__ obs,
                                                const float* __restrict__ Wls,
                                                const float* __restrict__ b_logstd,
                                                const float* __restrict__ pm,
                                                const float* __restrict__ pls,
                                                float* __restrict__ o_pm,
                                                float* __restrict__ o_lstd,
                                                float* __restrict__ o_nls) {
    __shared__ float wobs[ACT * OBS];
    __shared__ float bls[ACT];
    int t = threadIdx.x;
    if (t < ACT * OBS) wobs[t] = Wls[(size_t)(t / OBS) * IN_DIM + (t % OBS)];
    if (t < ACT) bls[t] = b_logstd[t];
    __syncthreads();
    int row = blockIdx.x * 256 + t;           // 8192 rows
    float ob[OBS];
#pragma unroll
    for (int k = 0; k < OBS; k++) ob[k] = obs[(size_t)row * OBS + k];
#pragma unroll
    for (int n = 0; n < ACT; n++) {
        float a = bls[n];
#pragma unroll
        for (int k = 0; k < OBS; k++) a += ob[k] * wobs[n * OBS + k];
        o_nls[(size_t)row * ACT + n] += a;    // completes the atomic partials
    }
    // prev_mean copy + log_std tanh transform
    float4 p0 = *(const float4*)(pm + (size_t)row * ACT);
    float4 p1 = *(const float4*)(pm + (size_t)row * ACT + 4);
    *(float4*)(o_pm + (size_t)row * ACT) = p0;
    *(float4*)(o_pm + (size_t)row * ACT + 4) = p1;
    float4 l0 = *(const float4*)(pls + (size_t)row * ACT);
    float4 l1 = *(const float4*)(pls + (size_t)row * ACT + 4);
    float4 q0, q1;
    q0.x = -5.f + 3.5f * (tanhf(l0.x) + 1.f);
    q0.y = -5.f + 3.5f * (tanhf(l0.y) + 1.f);
    q0.z = -5.f + 3.5f * (tanhf(l0.z) + 1.f);
    q0.w = -5.f + 3.5f * (tanhf(l0.w) + 1.f);
    q1.x = -5.f + 3.5f * (tanhf(l1.x) + 1.f);
    q1.y = -5.f + 3.5f * (tanhf(l1.y) + 1.f);
    q1.z = -5.f + 3.5f * (tanhf(l1.z) + 1.f);
    q1.w = -5.f + 3.5f * (tanhf(l1.w) + 1.f);
    *(float4*)(o_lstd + (size_t)row * ACT) = q0;
    *(float4*)(o_lstd + (size_t)row * ACT + 4) = q1;
}

extern "C" void kernel_launch(void* const* d_in, const int* in_sizes, int n_in,
                              void* d_out, int out_size, void* d_ws, size_t ws_size,
                              hipStream_t stream) {
    const float* obs         = (const float*)d_in[0];
    const float* hidden0     = (const float*)d_in[1];
    const float* prev_mean   = (const float*)d_in[2];
    const float* prev_logstd = (const float*)d_in[3];
    const float* W_mean      = (const float*)d_in[4];
    const float* b_mean      = (const float*)d_in[5];
    const float* W_logstd    = (const float*)d_in[6];
    const float* b_logstd    = (const float*)d_in[7];

    float* out   = (float*)d_out;
    float* o_pm  = out + O_PM;
    float* o_ls  = out + O_LS;
    float* o_nh  = out + O_NH;
    float* o_nm  = out + O_NM;
    float* o_nls = out + O_NLS;
    u16*   ws    = (u16*)d_ws;

    int packed = (ws != nullptr && ws_size >= WSP_BYTES) ? 1 : 0;

    if (packed) {
        k_pack<<<(WSP_TOTAL + 255) / 256, 256, 0, stream>>>(W_mean, ws);
    }
    hipMemsetAsync(o_nls, 0, (size_t)BATCH * ACT * sizeof(float), stream);
    k_fused<<<dim3(BATCH / BM, NL + 1), 512, 0, stream>>>(
        hidden0, W_mean, ws, W_logstd, b_mean, o_nh, o_nls, o_nm, packed);
    k_block0<<<BATCH / B0_ROWS, 256, 0, stream>>>(obs, W_mean, b_mean, o_nh);
    k_finish<<<BATCH / 256, 256, 0, stream>>>(obs, W_logstd, b_logstd,
                                              prev_mean, prev_logstd,
                                              o_pm, o_ls, o_nls);
}

// Round 2
// 460.589 us; speedup vs baseline: 1.8187x; 1.8187x over previous
//
#include <hip/hip_runtime.h>
#include <math.h>

typedef unsigned short u16;
typedef unsigned int u32;
typedef __attribute__((ext_vector_type(8))) short short8;   // 8 bf16 = 4 VGPRs
typedef __attribute__((ext_vector_type(4))) float float4v;  // MFMA accum

// ---------- constants ----------
#define BATCH   8192
#define OBS     21
#define HID     512
#define NL      10
#define OVERALL 5632            // HID*(NL+1)
#define IN_DIM  5653            // OBS + OVERALL
#define ACT     8

// output element offsets (flat concat, fp32 elements)
#define O_PM   0
#define O_LS   65536
#define O_NH   131072
#define O_NM   (131072 + BATCH*OVERALL)     // 46268416
#define O_NLS  (O_NM + 65536)               // 46333952

// packed workspace: 10 x 512 x 512 bf16 weight blocks (K-contiguous)
#define WSP_TOTAL (10*512*512)
#define WSP_BYTES ((size_t)WSP_TOTAL * 2)

__device__ __forceinline__ u16 f2bf(float f) {
    u32 u = __float_as_uint(f);
    u32 r = (u + 0x7fffu + ((u >> 16) & 1u)) >> 16;   // RNE
    return (u16)r;
}
__device__ __forceinline__ u32 pkbf(float a, float b) {
    return (u32)f2bf(a) | ((u32)f2bf(b) << 16);
}
__device__ __forceinline__ void gload_lds16(const void* g, void* l) {
    __builtin_amdgcn_global_load_lds(
        (const __attribute__((address_space(1))) char*)g,
        (__attribute__((address_space(3))) char*)l, 16, 0, 0);
}
// slot swizzle with 16-row period: breaks the 4-row periodicity that made
// lanes n,n+4,n+8,n+12 collide (4-way) in the old (quad+n)&3 scheme.
__device__ __forceinline__ int swz4(int r) { return (r + (r >> 2)) & 3; }

// ---------- kernel 0: repack banded W_mean blocks fp32 -> bf16 ----------
__global__ __launch_bounds__(256) void k_pack(const float* __restrict__ Wm,
                                              u16* __restrict__ ws) {
    int idx = blockIdx.x * 256 + threadIdx.x;
    if (idx >= WSP_TOTAL) return;
    int z = idx >> 18;
    int rem = idx & 262143;
    int n = rem >> 9, k = rem & 511;
    float v = Wm[(size_t)(512 * (z + 1) + n) * IN_DIM + OBS + 512 * z + k];
    ws[idx] = f2bf(v);
}

// ---------- kernel 1: fused slice kernel -----------------------------------
// grid (64, 11): block = 128 batch rows (gm) x one 512-col X slice (z).
// Round-0 structure (LDS-staged A+B, 16 waves, wave tile 64x64) with a
// 2-phase double-buffered pipeline: stage tile k+1 BEFORE computing tile k;
// single raw s_barrier per K-step with the vmcnt(0) drain AFTER the MFMAs,
// so ~1500 cyc of LDS reads + MFMA cover the global_load_lds latency.
//  z<10 : GEMM band z+1 (BN=512) + logstd partial (waves 0-7)
//  z==10: logstd partial (waves 0-7) + new_mean band 11 (waves 8-15)
#define BM 128
#define BK 32
#define LDA 40                  // padded bf16 LDS rows for A
__global__ __launch_bounds__(1024, 4) void k_fused(
        const float* __restrict__ X,
        const float* __restrict__ Wm_raw,
        const u16* __restrict__ Wp,
        const float* __restrict__ Wls_raw,
        const float* __restrict__ b_mean,
        float* __restrict__ out_h,
        float* __restrict__ out_ls,
        float* __restrict__ out_mean,
        int packed) {
    __shared__ __attribute__((aligned(16))) u16 As[2][BM * LDA];   // 2 x 10 KB
    __shared__ __attribute__((aligned(16))) u16 Bs[2][512 * 32];   // 2 x 32 KB
    __shared__ __attribute__((aligned(16))) u16 Wt[16 * 520];      // 16.25 KB
    u16* Wt2 = (u16*)&Bs[0][0];              // z==10 only: mean slice aliases Bs

    int t = threadIdx.x;
    int w = t >> 6, lane = t & 63;
    int quad = lane >> 4, r16 = lane & 15;
    int gm = blockIdx.x * BM;
    int z = blockIdx.y;
    bool mainz = (z < 10);
    int wm = (w >> 3) * 64;                  // GEMM wave tile: 2 m-pos x 8 n-pos
    int wn = (w & 7) * 64;

    // ---- stage logstd slice (bf16) + (z==10) mean slice ----
    {
        int n = t >> 7;                      // 0..7
        int k4 = (t & 127) * 4;
        const float* wr = Wls_raw + (size_t)n * IN_DIM + OBS + z * 512 + k4;
        u16* dst = &Wt[n * 520 + k4];
        dst[0] = f2bf(wr[0]); dst[1] = f2bf(wr[1]);
        dst[2] = f2bf(wr[2]); dst[3] = f2bf(wr[3]);
        if (!mainz) {
            const float* wr2 = Wm_raw + (size_t)(OVERALL + n) * IN_DIM + OBS + z * 512 + k4;
            u16* d2 = &Wt2[n * 520 + k4];
            d2[0] = f2bf(wr2[0]); d2[1] = f2bf(wr2[1]);
            d2[2] = f2bf(wr2[2]); d2[3] = f2bf(wr2[3]);
        }
    }

    // ---- A prefetch pointer: 1 float4 per thread per chunk ----
    int arow = t >> 3;                       // 0..127
    int acol = (t & 7) * 4;                  // 0..28
    const float* gA = X + (size_t)(gm + arow) * OVERALL + (size_t)z * 512 + acol;
    float4 areg = *(const float4*)(gA);      // chunk 0

    // B staging: both sides use the same swz4-based involution (src j, read s)
    auto stageB = [&](int buf, int kk) {
        if (packed) {
#pragma unroll
            for (int i2 = 0; i2 < 2; ++i2) {
                int base_row = i2 * 256 + w * 16;
                int row = base_row + (lane >> 2);
                int slot = lane & 3;
                int j = (slot - swz4(row)) & 3;    // logical k-chunk in this slot
                const u16* g = Wp + (size_t)z * 262144 + (size_t)row * 512 + kk + j * 8;
                gload_lds16(g, (char*)&Bs[buf][0] + base_row * 64);
            }
        } else {
#pragma unroll
            for (int i2 = 0; i2 < 2; ++i2) {
                int row = i2 * 256 + w * 16 + (lane >> 2);
                int slot = lane & 3;
                int j = (slot - swz4(row)) & 3;
                const float* g = Wm_raw + (size_t)(512 * (z + 1) + row) * IN_DIM
                                 + OBS + (size_t)z * 512 + kk + j * 8;
                uint4 q;
                q.x = pkbf(g[0], g[1]); q.y = pkbf(g[2], g[3]);
                q.z = pkbf(g[4], g[5]); q.w = pkbf(g[6], g[7]);
                *(uint4*)&Bs[buf][row * 32 + slot * 8] = q;
            }
        }
    };

    float4v acc[4][4];
#pragma unroll
    for (int i = 0; i < 4; i++)
#pragma unroll
        for (int j = 0; j < 4; j++) acc[i][j] = (float4v)0.f;
    float4v accE = (float4v)0.f;             // logstd (w<8) or mean (z==10, w>=8)

    // ---- prologue: stage tile 0 into buffer 0 ----
    {
        uint2 p;
        p.x = pkbf(areg.x, areg.y);
        p.y = pkbf(areg.z, areg.w);
        *(uint2*)&As[0][arow * LDA + acol] = p;
    }
    if (mainz) stageB(0, 0);
    areg = *(const float4*)(gA + BK);        // chunk 1
    asm volatile("s_waitcnt vmcnt(0) lgkmcnt(0)" ::: "memory");
    __builtin_amdgcn_s_barrier();

#pragma unroll 4
    for (int it = 0; it < 16; ++it) {
        const int cur = it & 1;
        const int k0 = it * BK;
        // ---- stage NEXT tile into buffer cur^1 (before compute) ----
        if (it < 15) {
            uint2 p;
            p.x = pkbf(areg.x, areg.y);
            p.y = pkbf(areg.z, areg.w);
            *(uint2*)&As[cur ^ 1][arow * LDA + acol] = p;
            if (mainz) stageB(cur ^ 1, k0 + BK);
            if (it < 14) areg = *(const float4*)(gA + (it + 2) * BK);
        }
        // ---- compute CURRENT tile from buffer cur ----
        if (mainz) {
            short8 bfr[4];
#pragma unroll
            for (int j = 0; j < 4; j++) {
                int n = wn + j * 16 + r16;
                int s = (quad + swz4(n)) & 3;
                bfr[j] = *(const short8*)&Bs[cur][n * 32 + s * 8];
            }
#pragma unroll
            for (int i2 = 0; i2 < 4; i2++) {
                short8 af = *(const short8*)&As[cur][(wm + i2 * 16 + r16) * LDA + quad * 8];
#pragma unroll
                for (int j = 0; j < 4; j++)
                    acc[i2][j] = __builtin_amdgcn_mfma_f32_16x16x32_bf16(af, bfr[j], acc[i2][j], 0, 0, 0);
            }
        }
        if (w < 8) {                         // logstd partial: rows w*16..w*16+15
            short8 aL = *(const short8*)&As[cur][(w * 16 + r16) * LDA + quad * 8];
            short8 bL = *(const short8*)&Wt[r16 * 520 + k0 + quad * 8];
            accE = __builtin_amdgcn_mfma_f32_16x16x32_bf16(aL, bL, accE, 0, 0, 0);
        } else if (!mainz) {                 // mean band: rows (w-8)*16..
            short8 aL = *(const short8*)&As[cur][((w - 8) * 16 + r16) * LDA + quad * 8];
            short8 bL = *(const short8*)&Wt2[r16 * 520 + k0 + quad * 8];
            accE = __builtin_amdgcn_mfma_f32_16x16x32_bf16(aL, bL, accE, 0, 0, 0);
        }
        // ---- single drain+barrier per K-step, AFTER compute ----
        asm volatile("s_waitcnt vmcnt(0) lgkmcnt(0)" ::: "memory");
        __builtin_amdgcn_s_barrier();
    }

    // ---- epilogues.  C/D layout: col = lane&15, row = quad*4 + reg ----
    if (mainz) {
        int colblock = (z + 1) * 512;
#pragma unroll
        for (int j = 0; j < 4; j++) {
            int n_loc = wn + j * 16 + r16;
            float bias = b_mean[colblock + n_loc];
#pragma unroll
            for (int i2 = 0; i2 < 4; i2++) {
                int m0 = gm + wm + i2 * 16 + quad * 4;
#pragma unroll
                for (int r = 0; r < 4; r++) {
                    float v = acc[i2][j][r] + bias;
                    out_h[(size_t)(m0 + r) * OVERALL + colblock + n_loc] = fmaxf(v, 0.f);
                }
            }
        }
    }
    if (w < 8) {                             // logstd partial -> atomic
        if (r16 < ACT) {
#pragma unroll
            for (int r = 0; r < 4; r++) {
                int row = gm + w * 16 + quad * 4 + r;
                atomicAdd(&out_ls[(size_t)row * ACT + r16], accE[r]);
            }
        }
    } else if (!mainz) {                     // mean: exact, direct store
        if (r16 < ACT) {
            float bias = b_mean[OVERALL + r16];
#pragma unroll
            for (int r = 0; r < 4; r++) {
                int row = gm + (w - 8) * 16 + quad * 4 + r;
                out_mean[(size_t)row * ACT + r16] = accE[r] + bias;
            }
        }
    }
}

// ---------- kernel 2: band block 0 (obs -> new_hidden cols 0..511) ----------
#define B0_ROWS 32
__global__ __launch_bounds__(256) void k_block0(const float* __restrict__ obs,
                                                const float* __restrict__ Wm,
                                                const float* __restrict__ b_mean,
                                                float* __restrict__ out_h) {
    __shared__ float w0[OBS * 512];           // transposed [k][n]
    __shared__ float bias_s[512];
    __shared__ float obs_s[B0_ROWS * OBS];
    int t = threadIdx.x;
    int b0 = blockIdx.x * B0_ROWS;
    for (int i = t; i < OBS * 512; i += 256) {
        int n = i / OBS, k = i - n * OBS;
        w0[k * 512 + n] = Wm[(size_t)n * IN_DIM + k];
    }
    for (int i = t; i < 512; i += 256) bias_s[i] = b_mean[i];
    for (int i = t; i < B0_ROWS * OBS; i += 256) obs_s[i] = obs[(size_t)b0 * OBS + i];
    __syncthreads();

    int n0 = (t & 127) * 4;
    int rh = t >> 7;
#pragma unroll 4
    for (int r = 0; r < 16; r++) {
        int row = rh * 16 + r;
        float acc0 = bias_s[n0], acc1 = bias_s[n0 + 1];
        float acc2 = bias_s[n0 + 2], acc3 = bias_s[n0 + 3];
#pragma unroll
        for (int k = 0; k < OBS; k++) {
            float xo = obs_s[row * OBS + k];
            const float* wr = &w0[k * 512 + n0];
            acc0 += xo * wr[0]; acc1 += xo * wr[1];
            acc2 += xo * wr[2]; acc3 += xo * wr[3];
        }
        float4 o;
        o.x = fmaxf(acc0, 0.f); o.y = fmaxf(acc1, 0.f);
        o.z = fmaxf(acc2, 0.f); o.w = fmaxf(acc3, 0.f);
        *(float4*)&out_h[(size_t)(b0 + row) * OVERALL + n0] = o;
    }
}

// ---------- kernel 3: finisher: logstd obs-part + bias, tanh, copy ----------
__global__ __launch_bounds__(256) void k_finish(const float* __restrict__ obs,
                                                const float* __restrict__ Wls,
                                                const float* __restrict__ b_logstd,
                                                const float* __restrict__ pm,
                                                const float* __restrict__ pls,
                                                float* __restrict__ o_pm,
                                                float* __restrict__ o_lstd,
                                                float* __restrict__ o_nls) {
    __shared__ float wobs[ACT * OBS];
    __shared__ float bls[ACT];
    int t = threadIdx.x;
    if (t < ACT * OBS) wobs[t] = Wls[(size_t)(t / OBS) * IN_DIM + (t % OBS)];
    if (t < ACT) bls[t] = b_logstd[t];
    __syncthreads();
    int row = blockIdx.x * 256 + t;           // 8192 rows
    float ob[OBS];
#pragma unroll
    for (int k = 0; k < OBS; k++) ob[k] = obs[(size_t)row * OBS + k];
#pragma unroll
    for (int n = 0; n < ACT; n++) {
        float a = bls[n];
#pragma unroll
        for (int k = 0; k < OBS; k++) a += ob[k] * wobs[n * OBS + k];
        o_nls[(size_t)row * ACT + n] += a;    // completes the atomic partials
    }
    // prev_mean copy + log_std tanh transform
    float4 p0 = *(const float4*)(pm + (size_t)row * ACT);
    float4 p1 = *(const float4*)(pm + (size_t)row * ACT + 4);
    *(float4*)(o_pm + (size_t)row * ACT) = p0;
    *(float4*)(o_pm + (size_t)row * ACT + 4) = p1;
    float4 l0 = *(const float4*)(pls + (size_t)row * ACT);
    float4 l1 = *(const float4*)(pls + (size_t)row * ACT + 4);
    float4 q0, q1;
    q0.x = -5.f + 3.5f * (tanhf(l0.x) + 1.f);
    q0.y = -5.f + 3.5f * (tanhf(l0.y) + 1.f);
    q0.z = -5.f + 3.5f * (tanhf(l0.z) + 1.f);
    q0.w = -5.f + 3.5f * (tanhf(l0.w) + 1.f);
    q1.x = -5.f + 3.5f * (tanhf(l1.x) + 1.f);
    q1.y = -5.f + 3.5f * (tanhf(l1.y) + 1.f);
    q1.z = -5.f + 3.5f * (tanhf(l1.z) + 1.f);
    q1.w = -5.f + 3.5f * (tanhf(l1.w) + 1.f);
    *(float4*)(o_lstd + (size_t)row * ACT) = q0;
    *(float4*)(o_lstd + (size_t)row * ACT + 4) = q1;
}

extern "C" void kernel_launch(void* const* d_in, const int* in_sizes, int n_in,
                              void* d_out, int out_size, void* d_ws, size_t ws_size,
                              hipStream_t stream) {
    const float* obs         = (const float*)d_in[0];
    const float* hidden0     = (const float*)d_in[1];
    const float* prev_mean   = (const float*)d_in[2];
    const float* prev_logstd = (const float*)d_in[3];
    const float* W_mean      = (const float*)d_in[4];
    const float* b_mean      = (const float*)d_in[5];
    const float* W_logstd    = (const float*)d_in[6];
    const float* b_logstd    = (const float*)d_in[7];

    float* out   = (float*)d_out;
    float* o_pm  = out + O_PM;
    float* o_ls  = out + O_LS;
    float* o_nh  = out + O_NH;
    float* o_nm  = out + O_NM;
    float* o_nls = out + O_NLS;
    u16*   ws    = (u16*)d_ws;

    int packed = (ws != nullptr && ws_size >= WSP_BYTES) ? 1 : 0;

    if (packed) {
        k_pack<<<(WSP_TOTAL + 255) / 256, 256, 0, stream>>>(W_mean, ws);
    }
    hipMemsetAsync(o_nls, 0, (size_t)BATCH * ACT * sizeof(float), stream);
    k_fused<<<dim3(BATCH / BM, NL + 1), 1024, 0, stream>>>(
        hidden0, W_mean, ws, W_logstd, b_mean, o_nh, o_nls, o_nm, packed);
    k_block0<<<BATCH / B0_ROWS, 256, 0, stream>>>(obs, W_mean, b_mean, o_nh);
    k_finish<<<BATCH / 256, 256, 0, stream>>>(obs, W_logstd, b_logstd,
                                              prev_mean, prev_logstd,
                                              o_pm, o_ls, o_nls);
}